// Round 2
// baseline (494.784 us; speedup 1.0000x reference)
//
#include <hip/hip_runtime.h>
#include <math.h>

#define BATCH   8
#define SEQ     4096
#define DM      512
#define NP      256
#define M_TOT   (BATCH * SEQ)     // 32768
#define CHUNKS  128
#define CHUNK_LEN 32              // SEQ / CHUNKS

// ---------------------------------------------------------------------------
// Fused projection GEMM: out[M,N] = X[M,512] @ W[512,N] + bias[N]
// BM=128, BN=64, BK=32, 256 threads, 8x4 outputs per thread. fp32 vector ALU
// (no fp32 MFMA on CDNA4).
// ---------------------------------------------------------------------------
template <int N>
__global__ __launch_bounds__(256) void gemm_proj(const float* __restrict__ X,
                                                 const float* __restrict__ W,
                                                 const float* __restrict__ bias,
                                                 float* __restrict__ out) {
    __shared__ float As[32][132];  // transposed X tile [k][m], +4 pad
    __shared__ float Bs[32][68];   // W tile [k][n], +4 pad

    const int bm  = blockIdx.x;          // 0..255  (M/128)
    const int bn  = blockIdx.y;          // 0..N/64-1
    const int tid = threadIdx.x;
    const int tm  = tid >> 4;            // 0..15 -> 8 rows each
    const int tn  = tid & 15;            // 0..15 -> 4 cols each

    float acc[8][4];
#pragma unroll
    for (int i = 0; i < 8; ++i)
#pragma unroll
        for (int j = 0; j < 4; ++j) acc[i][j] = 0.0f;

    for (int k0 = 0; k0 < DM; k0 += 32) {
        // stage X tile (128 rows x 32 k), transposed into As[k][m]
#pragma unroll
        for (int i = 0; i < 4; ++i) {
            int idx = tid + i * 256;          // 0..1023 float4 slots
            int row = idx >> 3;               // 0..127
            int kq  = idx & 7;                // 0..7 (float4 along k)
            float4 v = *(const float4*)(X + (size_t)(bm * 128 + row) * DM + k0 + kq * 4);
            As[kq * 4 + 0][row] = v.x;
            As[kq * 4 + 1][row] = v.y;
            As[kq * 4 + 2][row] = v.z;
            As[kq * 4 + 3][row] = v.w;
        }
        // stage W tile (32 k x 64 n)
#pragma unroll
        for (int i = 0; i < 2; ++i) {
            int idx = tid + i * 256;          // 0..511 float4 slots
            int kk  = idx >> 4;               // 0..31
            int cq  = idx & 15;               // 0..15
            float4 v = *(const float4*)(W + (size_t)(k0 + kk) * N + bn * 64 + cq * 4);
            *(float4*)&Bs[kk][cq * 4] = v;
        }
        __syncthreads();

#pragma unroll
        for (int kk = 0; kk < 32; ++kk) {
            float4 a0 = *(const float4*)&As[kk][tm * 8];
            float4 a1 = *(const float4*)&As[kk][tm * 8 + 4];
            float4 b  = *(const float4*)&Bs[kk][tn * 4];
            float av[8] = {a0.x, a0.y, a0.z, a0.w, a1.x, a1.y, a1.z, a1.w};
            float bv[4] = {b.x, b.y, b.z, b.w};
#pragma unroll
            for (int i = 0; i < 8; ++i)
#pragma unroll
                for (int j = 0; j < 4; ++j) acc[i][j] = fmaf(av[i], bv[j], acc[i][j]);
        }
        __syncthreads();
    }

    float4 bv = *(const float4*)(bias + bn * 64 + tn * 4);
#pragma unroll
    for (int i = 0; i < 8; ++i) {
        int row = bm * 128 + tm * 8 + i;
        float4 r;
        r.x = acc[i][0] + bv.x;
        r.y = acc[i][1] + bv.y;
        r.z = acc[i][2] + bv.z;
        r.w = acc[i][3] + bv.w;
        *(float4*)(out + (size_t)row * N + bn * 64 + tn * 4) = r;
    }
}

// ---------------------------------------------------------------------------
// decay[m] = sigmoid(dot(X[m,:], Wd) + bd). One wave per row, 4 rows/block.
// ---------------------------------------------------------------------------
__global__ __launch_bounds__(256) void decay_kernel(const float* __restrict__ X,
                                                    const float* __restrict__ Wd,
                                                    const float* __restrict__ bd,
                                                    float* __restrict__ dec) {
    const int wave = threadIdx.x >> 6;
    const int lane = threadIdx.x & 63;
    const int row  = blockIdx.x * 4 + wave;
    const float* xr = X + (size_t)row * DM;
    float sum = 0.0f;
#pragma unroll
    for (int j = 0; j < 8; ++j) sum += xr[lane + 64 * j] * Wd[lane + 64 * j];
#pragma unroll
    for (int off = 32; off > 0; off >>= 1) sum += __shfl_down(sum, off, 64);
    if (lane == 0) {
        float z = sum + bd[0];
        dec[row] = 1.0f / (1.0f + __expf(-z));
    }
}

// ---------------------------------------------------------------------------
// Phase 1: per-chunk local scan (h starts at 0). Overwrites out (which holds
// inj) with local states; emits per-chunk operator (theta sum, decay product)
// and the chunk's final local state.
// ---------------------------------------------------------------------------
__global__ __launch_bounds__(256) void scan_phase1(const float* __restrict__ angles,
                                                   const float* __restrict__ decays,
                                                   float* __restrict__ out,  // [B,T,P,2]
                                                   float* __restrict__ thetaC,
                                                   float2* __restrict__ hend,
                                                   float* __restrict__ Dprod) {
    const int b = blockIdx.x / CHUNKS;
    const int c = blockIdx.x % CHUNKS;
    const int p = threadIdx.x;
    const int t0 = c * CHUNK_LEN;
    float2* out2 = (float2*)out;

    float h0 = 0.0f, h1 = 0.0f, th = 0.0f, dc = 1.0f;
#pragma unroll 4
    for (int i = 0; i < CHUNK_LEN; ++i) {
        const int t = t0 + i;
        const size_t idx = (size_t)(b * SEQ + t) * NP + p;
        float a = angles[idx];
        float d = decays[b * SEQ + t];
        float2 u = out2[idx];
        float s, cc;
        __sincosf(a, &s, &cc);
        float he = cc * h0 - s * h1;
        float ho = s * h0 + cc * h1;
        h0 = fmaf(d, he, u.x);
        h1 = fmaf(d, ho, u.y);
        out2[idx] = make_float2(h0, h1);
        th += a;
        dc *= d;
    }
    const size_t cidx = (size_t)(b * CHUNKS + c) * NP + p;
    thetaC[cidx] = th;
    hend[cidx]   = make_float2(h0, h1);
    if (p == 0) Dprod[b * CHUNKS + c] = dc;
}

// ---------------------------------------------------------------------------
// Phase 2: sequential scan over chunk operators (128 per batch). Emits the
// entry state of every chunk. Tiny kernel.
// ---------------------------------------------------------------------------
__global__ __launch_bounds__(256) void scan_chunks(const float* __restrict__ thetaC,
                                                   const float2* __restrict__ hend,
                                                   const float* __restrict__ Dprod,
                                                   float2* __restrict__ hentry) {
    const int b = blockIdx.x;
    const int p = threadIdx.x;
    float h0 = 0.0f, h1 = 0.0f;
    for (int c = 0; c < CHUNKS; ++c) {
        const size_t cidx = (size_t)(b * CHUNKS + c) * NP + p;
        hentry[cidx] = make_float2(h0, h1);
        float th = thetaC[cidx];
        float D  = Dprod[b * CHUNKS + c];
        float2 he = hend[cidx];
        float s, cc;
        __sincosf(th, &s, &cc);
        float n0 = fmaf(D, cc * h0 - s * h1, he.x);
        float n1 = fmaf(D, s * h0 + cc * h1, he.y);
        h0 = n0;
        h1 = n1;
    }
}

// ---------------------------------------------------------------------------
// Phase 3: fixup. h_t = local_t + (prod_{s<=t} A_s) h_entry. Iterate
// v <- d_t R(a_t) v starting from the chunk entry state, add to out.
// ---------------------------------------------------------------------------
__global__ __launch_bounds__(256) void scan_fixup(const float* __restrict__ angles,
                                                  const float* __restrict__ decays,
                                                  const float2* __restrict__ hentry,
                                                  float* __restrict__ out) {
    const int b = blockIdx.x / CHUNKS;
    const int c = blockIdx.x % CHUNKS;
    if (c == 0) return;  // chunk 0 entry state is zero; local result is final
    const int p = threadIdx.x;
    const int t0 = c * CHUNK_LEN;
    float2* out2 = (float2*)out;

    float2 v = hentry[(size_t)(b * CHUNKS + c) * NP + p];
#pragma unroll 4
    for (int i = 0; i < CHUNK_LEN; ++i) {
        const int t = t0 + i;
        const size_t idx = (size_t)(b * SEQ + t) * NP + p;
        float a = angles[idx];
        float d = decays[b * SEQ + t];
        float s, cc;
        __sincosf(a, &s, &cc);
        float n0 = d * (cc * v.x - s * v.y);
        float n1 = d * (s * v.x + cc * v.y);
        v = make_float2(n0, n1);
        float2 o = out2[idx];
        o.x += v.x;
        o.y += v.y;
        out2[idx] = o;
    }
}

// ---------------------------------------------------------------------------
extern "C" void kernel_launch(void* const* d_in, const int* in_sizes, int n_in,
                              void* d_out, int out_size, void* d_ws, size_t ws_size,
                              hipStream_t stream) {
    const float* x  = (const float*)d_in[0];  // [8,4096,512]
    const float* Wa = (const float*)d_in[1];  // [512,256]
    const float* ba = (const float*)d_in[2];  // [256]
    const float* Wd = (const float*)d_in[3];  // [512,1]
    const float* bd = (const float*)d_in[4];  // [1]
    const float* Wi = (const float*)d_in[5];  // [512,512]
    const float* bi = (const float*)d_in[6];  // [512]
    float* out = (float*)d_out;               // [8,4096,512] fp32

    char* ws = (char*)d_ws;
    // ws layout (bytes) — CORRECTED sizes (B*C*P = 262,144 elements):
    float*  angles = (float*)(ws);                    // 33,554,432  [B,T,P]   fp32
    float*  decays = (float*)(ws + 33554432);         //    131,072  [B,T]     fp32
    float*  thetaC = (float*)(ws + 33685504);         //  1,048,576  [B,C,P]   fp32
    float2* hend   = (float2*)(ws + 34734080);        //  2,097,152  [B,C,P]   float2
    float*  Dprod  = (float*)(ws + 36831232);         //      4,096  [B,C]     fp32
    float2* hentry = (float2*)(ws + 36835328);        //  2,097,152  [B,C,P]   float2
    // total: 38,932,480 B

    // Projections
    gemm_proj<NP><<<dim3(M_TOT / 128, NP / 64), 256, 0, stream>>>(x, Wa, ba, angles);
    gemm_proj<DM><<<dim3(M_TOT / 128, DM / 64), 256, 0, stream>>>(x, Wi, bi, out);  // inj -> out
    decay_kernel<<<M_TOT / 4, 256, 0, stream>>>(x, Wd, bd, decays);

    // Chunked parallel scan
    scan_phase1<<<BATCH * CHUNKS, 256, 0, stream>>>(angles, decays, out, thetaC, hend, Dprod);
    scan_chunks<<<BATCH, 256, 0, stream>>>(thetaC, hend, Dprod, hentry);
    scan_fixup<<<BATCH * CHUNKS, 256, 0, stream>>>(angles, decays, hentry, out);
}

// Round 3
// 232.404 us; speedup vs baseline: 2.1290x; 2.1290x over previous
//
#include <hip/hip_runtime.h>
#include <math.h>

typedef _Float16 half_t;
typedef __attribute__((ext_vector_type(8))) _Float16 half8;
typedef __attribute__((ext_vector_type(4))) _Float16 half4;
typedef __attribute__((ext_vector_type(4))) float floatx4;

#define BATCH   8
#define SEQ     4096
#define DM      512
#define NP      256
#define M_TOT   32768
#define NTOT    768          // 512 inj cols + 256 angle cols
#define CHUNKS  128
#define CHUNK_LEN 32

// direct global->LDS DMA, 16 B per lane; lds dest = wave-uniform base + lane*16
__device__ __forceinline__ void async_load16(const void* g, void* l) {
    __builtin_amdgcn_global_load_lds((const __attribute__((address_space(1))) void*)g,
                                     (__attribute__((address_space(3))) void*)l,
                                     16, 0, 0);
}

// ---------------------------------------------------------------------------
// decay[m] = sigmoid(dot(X[m,:], Wd) + bd), fused with x fp32->fp16 convert.
// One wave per row, 4 rows/block.
// ---------------------------------------------------------------------------
__global__ __launch_bounds__(256) void decay_convert(const float* __restrict__ X,
                                                     const float* __restrict__ Wd,
                                                     const float* __restrict__ bd,
                                                     float* __restrict__ dec,
                                                     half_t* __restrict__ Xh) {
    const int wave = threadIdx.x >> 6;
    const int lane = threadIdx.x & 63;
    const int row  = blockIdx.x * 4 + wave;
    const float4* xr = (const float4*)(X + (size_t)row * DM);
    const float4* wd = (const float4*)Wd;
    float sum = 0.0f;
#pragma unroll
    for (int i = 0; i < 2; ++i) {
        const int c = lane + i * 64;            // float4 chunk 0..127
        float4 v = xr[c];
        float4 w = wd[c];
        sum += v.x * w.x + v.y * w.y + v.z * w.z + v.w * w.w;
        half4 h = {(half_t)v.x, (half_t)v.y, (half_t)v.z, (half_t)v.w};
        *(half4*)(Xh + (size_t)row * DM + c * 4) = h;
    }
#pragma unroll
    for (int off = 32; off > 0; off >>= 1) sum += __shfl_down(sum, off, 64);
    if (lane == 0) {
        float z = sum + bd[0];
        dec[row] = 1.0f / (1.0f + __expf(-z));
    }
}

// ---------------------------------------------------------------------------
// Build Wcat_t[768][512] fp16 = [Wi^T ; Wa^T]  (B^T layout: row n, contiguous k)
// ---------------------------------------------------------------------------
__global__ __launch_bounds__(256) void wcat_transpose(const float* __restrict__ Wi,
                                                      const float* __restrict__ Wa,
                                                      half_t* __restrict__ Wt) {
    const int idx = blockIdx.x * 256 + threadIdx.x;  // 0..768*512-1
    const int n = idx >> 9;          // 0..767
    const int k = idx & 511;
    float v = (n < DM) ? Wi[(size_t)k * DM + n] : Wa[(size_t)k * NP + (n - DM)];
    Wt[idx] = (half_t)v;
}

// ---------------------------------------------------------------------------
// Fused projection GEMM via fp16 MFMA. C[M,768] = Xh[M,512] @ Wt^T + bias.
// BM=BN=128, BK=32. 4 waves, each 64x64 = 4x4 MFMA tiles of 16x16x32.
// A,B tiles staged [row][32k] fp16 (8 KB each) via global_load_lds width 16,
// 16B quarters XOR-swizzled by ((row>>1)&3) so ds_read_b128 frag reads are
// conflict-free (<=2-way) without padding.
// Cols 0..511 -> inj (fp32, into d_out); cols 512..767 -> angles (fp16).
// ---------------------------------------------------------------------------
__global__ __launch_bounds__(256) void gemm_fused(const half_t* __restrict__ Xh,
                                                  const half_t* __restrict__ Wt,
                                                  const float* __restrict__ bi,
                                                  const float* __restrict__ ba,
                                                  float* __restrict__ out,
                                                  half_t* __restrict__ angles) {
    __shared__ __align__(16) char As[8192];
    __shared__ __align__(16) char Bs[8192];

    const int bm   = blockIdx.x;         // 0..255
    const int bn   = blockIdx.y;         // 0..5
    const int tid  = threadIdx.x;
    const int wave = tid >> 6;
    const int lane = tid & 63;
    const int quad = lane >> 4;
    const int l16  = lane & 15;
    const int wrow = wave >> 1;          // 0..1
    const int wcol = wave & 1;           // 0..1

    floatx4 acc[4][4];
#pragma unroll
    for (int i = 0; i < 4; ++i)
#pragma unroll
        for (int j = 0; j < 4; ++j) acc[i][j] = (floatx4){0.f, 0.f, 0.f, 0.f};

    // staging slots: slot s in [0,512): row r=s>>2, phys 16B-quarter kqp=s&3,
    // holds global k-quarter kql = kqp ^ ((r>>1)&3). This thread serves slots
    // s0 = wave*128+lane and s1 = s0+64 (lds base must be wave-uniform).
    const int s0 = wave * 128 + lane;
    const int s1 = s0 + 64;
    const int r0 = s0 >> 2, kql0 = (s0 & 3) ^ ((r0 >> 1) & 3);
    const int r1 = s1 >> 2, kql1 = (s1 & 3) ^ ((r1 >> 1) & 3);
    const half_t* gA0 = Xh + (size_t)(bm * 128 + r0) * DM + kql0 * 8;
    const half_t* gA1 = Xh + (size_t)(bm * 128 + r1) * DM + kql1 * 8;
    const half_t* gB0 = Wt + (size_t)(bn * 128 + r0) * DM + kql0 * 8;
    const half_t* gB1 = Wt + (size_t)(bn * 128 + r1) * DM + kql1 * 8;
    char* lA0 = As + wave * 2048;
    char* lA1 = As + wave * 2048 + 1024;
    char* lB0 = Bs + wave * 2048;
    char* lB1 = Bs + wave * 2048 + 1024;

    for (int k0 = 0; k0 < DM; k0 += 32) {
        async_load16(gA0 + k0, lA0);
        async_load16(gA1 + k0, lA1);
        async_load16(gB0 + k0, lB0);
        async_load16(gB1 + k0, lB1);
        __syncthreads();

        half8 af[4], bf[4];
#pragma unroll
        for (int mt = 0; mt < 4; ++mt) {
            const int r = wrow * 64 + mt * 16 + l16;
            af[mt] = *(const half8*)(As + r * 64 + ((quad ^ ((r >> 1) & 3)) << 4));
        }
#pragma unroll
        for (int nt = 0; nt < 4; ++nt) {
            const int r = wcol * 64 + nt * 16 + l16;
            bf[nt] = *(const half8*)(Bs + r * 64 + ((quad ^ ((r >> 1) & 3)) << 4));
        }
#pragma unroll
        for (int mt = 0; mt < 4; ++mt)
#pragma unroll
            for (int nt = 0; nt < 4; ++nt)
                acc[mt][nt] = __builtin_amdgcn_mfma_f32_16x16x32_f16(af[mt], bf[nt],
                                                                     acc[mt][nt], 0, 0, 0);
        __syncthreads();
    }

    // epilogue: C/D layout col=lane&15, row=quad*4+reg
    const int colbase = bn * 128 + wcol * 64;
#pragma unroll
    for (int nt = 0; nt < 4; ++nt) {
        const int col = colbase + nt * 16 + l16;
        const bool is_inj = col < DM;                 // uniform per 16-tile
        const float bias = is_inj ? bi[col] : ba[col - DM];
#pragma unroll
        for (int mt = 0; mt < 4; ++mt) {
            const int rowb = bm * 128 + wrow * 64 + mt * 16 + quad * 4;
#pragma unroll
            for (int r = 0; r < 4; ++r) {
                const float v = acc[mt][nt][r] + bias;
                const int row = rowb + r;
                if (is_inj) out[(size_t)row * DM + col] = v;
                else        angles[(size_t)row * NP + (col - DM)] = (half_t)v;
            }
        }
    }
}

// ---------------------------------------------------------------------------
// Phase 1: per-chunk local scan; overwrites out (inj) with local states.
// ---------------------------------------------------------------------------
__global__ __launch_bounds__(256) void scan_phase1(const half_t* __restrict__ angles,
                                                   const float* __restrict__ decays,
                                                   float* __restrict__ out,
                                                   float* __restrict__ thetaC,
                                                   float2* __restrict__ hend,
                                                   float* __restrict__ Dprod) {
    const int b = blockIdx.x / CHUNKS;
    const int c = blockIdx.x % CHUNKS;
    const int p = threadIdx.x;
    const int t0 = c * CHUNK_LEN;
    float2* out2 = (float2*)out;

    float h0 = 0.0f, h1 = 0.0f, th = 0.0f, dc = 1.0f;
#pragma unroll 4
    for (int i = 0; i < CHUNK_LEN; ++i) {
        const int t = t0 + i;
        const size_t idx = (size_t)(b * SEQ + t) * NP + p;
        float a = (float)angles[idx];
        float d = decays[b * SEQ + t];
        float2 u = out2[idx];
        float s, cc;
        __sincosf(a, &s, &cc);
        float he = cc * h0 - s * h1;
        float ho = s * h0 + cc * h1;
        h0 = fmaf(d, he, u.x);
        h1 = fmaf(d, ho, u.y);
        out2[idx] = make_float2(h0, h1);
        th += a;
        dc *= d;
    }
    const size_t cidx = (size_t)(b * CHUNKS + c) * NP + p;
    thetaC[cidx] = th;
    hend[cidx]   = make_float2(h0, h1);
    if (p == 0) Dprod[b * CHUNKS + c] = dc;
}

// ---------------------------------------------------------------------------
// Phase 2: sequential scan over the 128 chunk operators per batch.
// ---------------------------------------------------------------------------
__global__ __launch_bounds__(256) void scan_chunks(const float* __restrict__ thetaC,
                                                   const float2* __restrict__ hend,
                                                   const float* __restrict__ Dprod,
                                                   float2* __restrict__ hentry) {
    const int b = blockIdx.x;
    const int p = threadIdx.x;
    float h0 = 0.0f, h1 = 0.0f;
    for (int c = 0; c < CHUNKS; ++c) {
        const size_t cidx = (size_t)(b * CHUNKS + c) * NP + p;
        hentry[cidx] = make_float2(h0, h1);
        float th = thetaC[cidx];
        float D  = Dprod[b * CHUNKS + c];
        float2 he = hend[cidx];
        float s, cc;
        __sincosf(th, &s, &cc);
        float n0 = fmaf(D, cc * h0 - s * h1, he.x);
        float n1 = fmaf(D, s * h0 + cc * h1, he.y);
        h0 = n0;
        h1 = n1;
    }
}

// ---------------------------------------------------------------------------
// Phase 3: fixup. out_t += (prod A) * h_entry.
// ---------------------------------------------------------------------------
__global__ __launch_bounds__(256) void scan_fixup(const half_t* __restrict__ angles,
                                                  const float* __restrict__ decays,
                                                  const float2* __restrict__ hentry,
                                                  float* __restrict__ out) {
    const int b = blockIdx.x / CHUNKS;
    const int c = blockIdx.x % CHUNKS;
    if (c == 0) return;
    const int p = threadIdx.x;
    const int t0 = c * CHUNK_LEN;
    float2* out2 = (float2*)out;

    float2 v = hentry[(size_t)(b * CHUNKS + c) * NP + p];
#pragma unroll 4
    for (int i = 0; i < CHUNK_LEN; ++i) {
        const int t = t0 + i;
        const size_t idx = (size_t)(b * SEQ + t) * NP + p;
        float a = (float)angles[idx];
        float d = decays[b * SEQ + t];
        float s, cc;
        __sincosf(a, &s, &cc);
        float n0 = d * (cc * v.x - s * v.y);
        float n1 = d * (s * v.x + cc * v.y);
        v = make_float2(n0, n1);
        float2 o = out2[idx];
        o.x += v.x;
        o.y += v.y;
        out2[idx] = o;
    }
}

// ---------------------------------------------------------------------------
extern "C" void kernel_launch(void* const* d_in, const int* in_sizes, int n_in,
                              void* d_out, int out_size, void* d_ws, size_t ws_size,
                              hipStream_t stream) {
    const float* x  = (const float*)d_in[0];
    const float* Wa = (const float*)d_in[1];
    const float* ba = (const float*)d_in[2];
    const float* Wd = (const float*)d_in[3];
    const float* bd = (const float*)d_in[4];
    const float* Wi = (const float*)d_in[5];
    const float* bi = (const float*)d_in[6];
    float* out = (float*)d_out;

    char* ws = (char*)d_ws;
    // ws layout. x_h is dead after gemm_fused; scan scratch overlays it.
    half_t* x_h     = (half_t*)(ws);                  // 33,554,432 B @ 0
    float*  thetaC  = (float*)(ws);                   //  1,048,576 B @ 0        (overlay)
    float2* hend    = (float2*)(ws + 1048576);        //  2,097,152 B            (overlay)
    float*  Dprod   = (float*)(ws + 3145728);         //      4,096 B            (overlay)
    float2* hentry  = (float2*)(ws + 3149824);        //  2,097,152 B            (overlay)
    half_t* angles  = (half_t*)(ws + 33554432);       // 16,777,216 B  [B,T,P] fp16
    float*  decays  = (float*)(ws + 50331648);        //    131,072 B  [B,T]
    half_t* Wcat_t  = (half_t*)(ws + 50462720);       //    786,432 B  [768][512] fp16
    // total: 51,249,152 B

    decay_convert<<<M_TOT / 4, 256, 0, stream>>>(x, Wd, bd, decays, x_h);
    wcat_transpose<<<(NTOT * DM) / 256, 256, 0, stream>>>(Wi, Wa, Wcat_t);
    gemm_fused<<<dim3(M_TOT / 128, NTOT / 128), 256, 0, stream>>>(x_h, Wcat_t, bi, ba, out, angles);

    scan_phase1<<<BATCH * CHUNKS, 256, 0, stream>>>(angles, decays, out, thetaC, hend, Dprod);
    scan_chunks<<<BATCH, 256, 0, stream>>>(thetaC, hend, Dprod, hentry);
    scan_fixup<<<BATCH * CHUNKS, 256, 0, stream>>>(angles, decays, hentry, out);
}